// Round 4
// baseline (117.464 us; speedup 1.0000x reference)
//
#include <hip/hip_runtime.h>
#include <hip/hip_fp16.h>
#include <math.h>

// MatchAttention fused forward — v5 (v3 + 2 pixel-head streams per thread).
// B=2, H=W=64 (N=4096), C=256, h=8 (Ch=32), 7x7=49 window.
//
// Ledger:
// - Load batches survive ONLY across a runtime-loop backedge with no
//   intervening control flow (R8 kept; R9/R10/R1-v2 collapsed).
// - TLP null (R0 5blk/CU 44us -> R2 8blk/CU 41us), VALU diet ~null (R2),
//   attn-write coalescing null (R3: L3 absorbs the scatter; reverted).
// - Remaining hypothesis: issue-side overlap. R1 capture: VALU-issue ~16us
//   + mem service ~25us ~= the 41us observed (additive, not overlapped);
//   Occupancy 33% => ~2.6 blocks/CU effective, TLP too thin.
// v5: two independent pixel-head streams per thread (x, x+32 of same row,
// same b,g -> shared kv base). Phases interleaved L1 L2 C1 C2 across the
// proven ty+=2 backedge: each wave always has a second dependency-free
// stream to issue during the other's vmcnt/DPP-chain stalls.
constexpr int B = 2, H = 64, W = 64, C = 256, NH = 8, CH = 32;
constexpr int R = 3, KW = 7, KK = 49, N = H * W;
constexpr float LOG2E = 1.4426950408889634f;

typedef _Float16 h16x2 __attribute__((ext_vector_type(2)));

template <int CTRL>
static __device__ __forceinline__ float dpp_mov(float v) {
  union { float f; int i; } u;
  u.f = v;
  u.i = __builtin_amdgcn_update_dpp(u.i, u.i, CTRL, 0xf, 0xf, true);
  return u.f;
}
#define DPP_QUAD_XOR1 0xB1     // quad_perm [1,0,3,2]
#define DPP_QUAD_XOR2 0x4E     // quad_perm [2,3,0,1]
#define DPP_HALF_MIRROR 0x141  // lane i -> 7-i within each 8-lane group

static __device__ __forceinline__ h16x2 h2n(__half2 x) {
  union { __half2 h; h16x2 n; } u;
  u.h = x;
  return u.n;
}

// pack k,v fp32 -> fp16 interleaved: [b][n][g][(k0..3 v0..3) x 8] = 128B.
// k is pre-scaled by log2(e): exp2(-log2e*sum|q-k|) == exp(-sum|q-k|).
__global__ void __launch_bounds__(256) pack_kv_kernel(
    const float* __restrict__ kp, const float* __restrict__ vp,
    __half* __restrict__ kv) {
  const int idx = blockIdx.x * 256 + threadIdx.x;  // 0..524287
  const int e8 = idx & 7;
  const int g = (idx >> 3) & 7;
  const int bn = idx >> 6;  // 0..8191 = b*N+n
  const float4 kf = *(const float4*)(kp + (size_t)bn * C + g * CH + e8 * 4);
  const float4 vf = *(const float4*)(vp + (size_t)bn * C + g * CH + e8 * 4);
  __half2 o[4];
  o[0] = __floats2half2_rn(kf.x * LOG2E, kf.y * LOG2E);
  o[1] = __floats2half2_rn(kf.z * LOG2E, kf.w * LOG2E);
  o[2] = __floats2half2_rn(vf.x, vf.y);
  o[3] = __floats2half2_rn(vf.z, vf.w);
  *(float4*)(kv + ((size_t)(bn * NH + g) * 64 + e8 * 8)) = *(float4*)o;
}

union KV { float4 f; __half2 h[4]; h16x2 n[4]; };

__global__ void __launch_bounds__(256, 2) match_attn_kernel(
    const float* __restrict__ moff, const float* __restrict__ qp,
    const __half* __restrict__ kvp, float* __restrict__ outp,
    float* __restrict__ attnp) {
  const int t = threadIdx.x;
  const int e8 = t & 7;  // which 4-channel slice of the head
  const int p = t >> 3;  // pixel within block, 0..31; streams at x=p, p+32

  // XCD swizzle: blk&7 ~ XCD; XCD x owns (b,g) pairs {2x,2x+1}.
  // Block = one full image row y for one (b,g): 64 pixel-heads, 2/thread.
  const int xcd = blockIdx.x & 7;
  const int rest = blockIdx.x >> 3;      // 0..127
  const int bg = xcd * 2 + (rest >> 6);  // 0..15
  const int y = rest & 63;
  const int g = bg & 7;
  const int b = bg >> 3;
  const int n0 = y * W + p;  // stream s pixel index = n0 + s*32

  // wave-uniform image base (b,g blockIdx-derived -> SGPR pair)
  const char* __restrict__ kvb =
      (const char*)kvp + (size_t)(b * N * NH + g) * 128;
  const int lane16 = e8 * 16;
  const int chn = g * CH + e8 * 4;
  const h16x2 one2 = {(_Float16)1.0f, (_Float16)1.0f};

  // per-stream state (all indexed by literal s after unroll -> registers)
  int cy[2], pxo[2][KW];
  __half2 q01[2], q23[2];
  float ev7[2][KW];
  float4 acc[2];
  float d0[2], d1[2];

#pragma unroll
  for (int s = 0; s < 2; ++s) {
    const int ns = n0 + s * 32;
    const int xs = p + s * 32;
    // rintf == jnp.round (half-to-even)
    const float2 off =
        *(const float2*)(moff + ((size_t)(b * N + ns) * NH + g) * 2);
    cy[s] = y + (int)rintf(off.x);
    const int cx = xs + (int)rintf(off.y);
#pragma unroll
    for (int i = 0; i < KW; ++i)
      pxo[s][i] = min(max(cx + i - R, 0), W - 1) << 10;  // pixel stride 1KB
    const float4 q0 = *(const float4*)(qp + (size_t)(b * N + ns) * C + chn);
    q01[s] = __floats2half2_rn(q0.x * LOG2E, q0.y * LOG2E);
    q23[s] = __floats2half2_rn(q0.z * LOG2E, q0.w * LOG2E);
#pragma unroll
    for (int i = 0; i < KW; ++i) ev7[s][i] = 0.f;
    acc[s] = {0.f, 0.f, 0.f, 0.f};
    d0[s] = 0.f;
    d1[s] = 0.f;
  }

  // row stride 64KB; per-lane channel chunk folded in
#define ROWBASE(s, iy) ((min(max(cy[s] + (iy)-R, 0), H - 1) << 16) + lane16)
#define LOADROW(buf, s, iy)                                       \
  {                                                               \
    const int _rb = ROWBASE(s, iy);                               \
    _Pragma("unroll") for (int ix = 0; ix < KW; ++ix)             \
        buf[ix].f = *(const float4*)(kvb + (_rb + pxo[s][ix]));   \
  }
#define COMPROW(buf, s, iy)                                                  \
  {                                                                          \
    const bool _own = ((iy) == e8);                                          \
    _Pragma("unroll") for (int ix = 0; ix < KW; ++ix) {                      \
      const h16x2 d01 = h2n(__habs2(__hsub2(q01[s], buf[ix].h[0])));         \
      const h16x2 d23 = h2n(__habs2(__hsub2(q23[s], buf[ix].h[1])));         \
      float sum = __builtin_amdgcn_fdot2(                                    \
          d01, one2, __builtin_amdgcn_fdot2(d23, one2, 0.0f, false), false); \
      sum += dpp_mov<DPP_QUAD_XOR1>(sum);                                    \
      sum += dpp_mov<DPP_QUAD_XOR2>(sum);                                    \
      sum += dpp_mov<DPP_HALF_MIRROR>(sum);                                  \
      const float e = __builtin_amdgcn_exp2f(-sum); /* sim<=0 */             \
      if (ix & 1) d1[s] += e; else d0[s] += e;                               \
      if (_own) ev7[s][ix] = e;                                              \
      const h16x2 v01 = buf[ix].n[2], v23 = buf[ix].n[3];                    \
      acc[s].x = fmaf(e, (float)v01.x, acc[s].x);                            \
      acc[s].y = fmaf(e, (float)v01.y, acc[s].y);                            \
      acc[s].z = fmaf(e, (float)v23.x, acc[s].z);                            \
      acc[s].w = fmaf(e, (float)v23.y, acc[s].w);                            \
    }                                                                        \
  }

  KV A[2][KW], Bf[2][KW];
  LOADROW(A[0], 0, 0)  // prologue: row 0 of both streams in flight
  LOADROW(A[1], 1, 0)
#pragma clang loop unroll(disable)
  for (int ty = 0; ty < KW - 1; ty += 2) {  // ty = 0,2,4 — runtime backedge
    LOADROW(Bf[0], 0, ty + 1)  // issue both streams' row ty+1
    LOADROW(Bf[1], 1, ty + 1)
    COMPROW(A[0], 0, ty)       // stream 2 compute fills stream 1's stalls
    COMPROW(A[1], 1, ty)
    LOADROW(A[0], 0, ty + 2)   // crosses the backedge -> cannot be sunk
    LOADROW(A[1], 1, ty + 2)
    COMPROW(Bf[0], 0, ty + 1)
    COMPROW(Bf[1], 1, ty + 1)
  }
  COMPROW(A[0], 0, KW - 1)     // epilogue: row 6
  COMPROW(A[1], 1, KW - 1)

#pragma unroll
  for (int s = 0; s < 2; ++s) {
    const int ns = n0 + s * 32;
    const float inv = 1.0f / (d0[s] + d1[s]);
    float4 o;
    o.x = acc[s].x * inv; o.y = acc[s].y * inv;
    o.z = acc[s].z * inv; o.w = acc[s].w * inv;
    *(float4*)(outp + (size_t)(b * N + ns) * C + chn) = o;
    // lane e8 (<7) writes window row e8 of attn, normalized, exactly once.
    // Direct scatter (v3 epilogue): L3 absorbs it; LDS version was slower.
    if (e8 < KW) {
      float* attn_row = attnp + ((size_t)(b * N + ns) * NH + g) * KK + e8 * KW;
#pragma unroll
      for (int ix = 0; ix < KW; ++ix) attn_row[ix] = ev7[s][ix] * inv;
    }
  }
}

extern "C" void kernel_launch(void* const* d_in, const int* in_sizes, int n_in,
                              void* d_out, int out_size, void* d_ws, size_t ws_size,
                              hipStream_t stream) {
  const float* moff = (const float*)d_in[0];  // [B,N,h,2]
  const float* q    = (const float*)d_in[1];  // [B,N,C]
  const float* k    = (const float*)d_in[2];  // [B,N,C]
  const float* v    = (const float*)d_in[3];  // [B,N,C]
  float* out  = (float*)d_out;            // [B,N,C]
  float* attn = out + (size_t)B * N * C;  // [B,N,h,K]
  __half* kv = (__half*)d_ws;             // packed fp16 kv, 8.4 MB

  pack_kv_kernel<<<B * N * NH * 8 / 256, 256, 0, stream>>>(k, v, kv);
  const int grid = B * NH * H;  // 1024 blocks of 256 threads, 2 px/thread
  match_attn_kernel<<<grid, 256, 0, stream>>>(moff, q, kv, out, attn);
}

// Round 5
// 110.779 us; speedup vs baseline: 1.0603x; 1.0603x over previous
//
#include <hip/hip_runtime.h>
#include <hip/hip_fp16.h>
#include <math.h>

// MatchAttention fused forward — v6 (v3 + true depth-2 prefetch).
// B=2, H=W=64 (N=4096), C=256, h=8 (Ch=32), 7x7=49 window.
//
// Ledger:
// - Load batches survive ONLY across a runtime-loop backedge with no
//   intervening control flow (R8 kept; R9/R10/R1-v2 collapsed; R1-v2's
//   collapse was launch_bounds(256,4)+conditional LOADROW, NOT the
//   period-3 rotation itself — that was a confound).
// - TLP null (R0->R2), 2-stream ILP negative (R4: 117.5us), VALU diet
//   ~3us (R2), attn-write coalescing null (R3: L3 absorbs the scatter).
// - v3 is depth-1: during COMPROW(ty) only row ty+1's 7 loads are in
//   flight (~250cy compute vs ~500+cy loaded-L2 gather latency).
// v6: period-3 A/B/C rotation, unconditional loads. The tail "row 7"
// load is legal — ROWBASE clamps iy, redundant reload (+14% tail
// traffic). Steady state: 14 loads outstanding during every COMPROW
// (vmcnt walk: C(t) drains row t's batch, rows t+1,t+2 remain).
// Discriminator: latency-stall-bound -> ~30-34us; L2-request-rate-bound
// -> ~45-47us. Collapse signature: VGPR < 80.
constexpr int B = 2, H = 64, W = 64, C = 256, NH = 8, CH = 32;
constexpr int R = 3, KW = 7, KK = 49, N = H * W;
constexpr int PIX = 32;  // pixel-heads per 256-thread block (8 lanes each)
constexpr float LOG2E = 1.4426950408889634f;

typedef _Float16 h16x2 __attribute__((ext_vector_type(2)));

template <int CTRL>
static __device__ __forceinline__ float dpp_mov(float v) {
  union { float f; int i; } u;
  u.f = v;
  u.i = __builtin_amdgcn_update_dpp(u.i, u.i, CTRL, 0xf, 0xf, true);
  return u.f;
}
#define DPP_QUAD_XOR1 0xB1     // quad_perm [1,0,3,2]
#define DPP_QUAD_XOR2 0x4E     // quad_perm [2,3,0,1]
#define DPP_HALF_MIRROR 0x141  // lane i -> 7-i within each 8-lane group

static __device__ __forceinline__ h16x2 h2n(__half2 x) {
  union { __half2 h; h16x2 n; } u;
  u.h = x;
  return u.n;
}

// pack k,v fp32 -> fp16 interleaved: [b][n][g][(k0..3 v0..3) x 8] = 128B.
// k is pre-scaled by log2(e): exp2(-log2e*sum|q-k|) == exp(-sum|q-k|),
// so the match kernel feeds the raw L1 sum straight into v_exp_f32.
// v stays unscaled.
__global__ void __launch_bounds__(256) pack_kv_kernel(
    const float* __restrict__ kp, const float* __restrict__ vp,
    __half* __restrict__ kv) {
  const int idx = blockIdx.x * 256 + threadIdx.x;  // 0..524287
  const int e8 = idx & 7;
  const int g = (idx >> 3) & 7;
  const int bn = idx >> 6;  // 0..8191 = b*N+n
  const float4 kf = *(const float4*)(kp + (size_t)bn * C + g * CH + e8 * 4);
  const float4 vf = *(const float4*)(vp + (size_t)bn * C + g * CH + e8 * 4);
  __half2 o[4];
  o[0] = __floats2half2_rn(kf.x * LOG2E, kf.y * LOG2E);
  o[1] = __floats2half2_rn(kf.z * LOG2E, kf.w * LOG2E);
  o[2] = __floats2half2_rn(vf.x, vf.y);
  o[3] = __floats2half2_rn(vf.z, vf.w);
  *(float4*)(kv + ((size_t)(bn * NH + g) * 64 + e8 * 8)) = *(float4*)o;
}

union KV { float4 f; __half2 h[4]; h16x2 n[4]; };

__global__ void __launch_bounds__(256, 2) match_attn_kernel(
    const float* __restrict__ moff, const float* __restrict__ qp,
    const __half* __restrict__ kvp, float* __restrict__ outp,
    float* __restrict__ attnp) {
  const int t = threadIdx.x;
  const int e8 = t & 7;  // which 4-channel slice of the head
  const int p = t >> 3;  // pixel within block, 0..31

  // XCD swizzle: blk&7 ~ XCD; XCD x owns (b,g) pairs {2x,2x+1}
  const int xcd = blockIdx.x & 7;
  const int rest = blockIdx.x >> 3;      // 0..255
  const int bg = xcd * 2 + (rest >> 7);  // 0..15
  const int slot = rest & 127;
  const int y = slot >> 1;
  const int x = (slot & 1) * PIX + p;
  const int g = bg & 7;
  const int b = bg >> 3;
  const int n = y * W + x;

  // per-pixel, per-head rounded (dy,dx); rintf == jnp.round (half-to-even)
  const float2 off = *(const float2*)(moff + ((size_t)(b * N + n) * NH + g) * 2);
  const int cy = y + (int)rintf(off.x);
  const int cx = x + (int)rintf(off.y);

  // clamped x offsets in BYTES (pixel stride 1024B)
  int pxo[KW];
#pragma unroll
  for (int i = 0; i < KW; ++i) pxo[i] = min(max(cx + i - R, 0), W - 1) << 10;
  // wave-uniform image base (b,g are blockIdx-derived -> SGPR pair);
  // per-lane terms live in the 32-bit voffset -> saddr-form loads.
  const char* __restrict__ kvb =
      (const char*)kvp + (size_t)(b * N * NH + g) * 128;
  const int lane16 = e8 * 16;

  const int chn = g * CH + e8 * 4;
  const float4 q0 = *(const float4*)(qp + (size_t)(b * N + n) * C + chn);
  const __half2 q01 = __floats2half2_rn(q0.x * LOG2E, q0.y * LOG2E);
  const __half2 q23 = __floats2half2_rn(q0.z * LOG2E, q0.w * LOG2E);
  const h16x2 one2 = {(_Float16)1.0f, (_Float16)1.0f};

  float ev7[KW];  // attn weights of the row this lane owns (lane e8 -> row e8)
#pragma unroll
  for (int i = 0; i < KW; ++i) ev7[i] = 0.f;
  float4 acc = {0.f, 0.f, 0.f, 0.f};  // unnormalized e-weighted V sum
  float d0 = 0.f, d1 = 0.f;           // two denom chains

  // row base (bytes, row stride 64KB) incl. per-lane channel chunk;
  // iy clamped to [0,H-1] -> out-of-range prefetch rows are legal reloads
#define ROWBASE(iy) ((min(max(cy + (iy)-R, 0), H - 1) << 16) + lane16)
#define LOADROW(buf, iy)                                      \
  {                                                           \
    const int _rb = ROWBASE(iy);                              \
    _Pragma("unroll") for (int ix = 0; ix < KW; ++ix)         \
        buf[ix].f = *(const float4*)(kvb + (_rb + pxo[ix]));  \
  }
#define COMPROW(buf, iy)                                                     \
  {                                                                          \
    const bool _own = ((iy) == e8);                                          \
    _Pragma("unroll") for (int ix = 0; ix < KW; ++ix) {                      \
      const h16x2 d01 = h2n(__habs2(__hsub2(q01, buf[ix].h[0])));            \
      const h16x2 d23 = h2n(__habs2(__hsub2(q23, buf[ix].h[1])));            \
      float s = __builtin_amdgcn_fdot2(                                      \
          d01, one2, __builtin_amdgcn_fdot2(d23, one2, 0.0f, false), false); \
      s += dpp_mov<DPP_QUAD_XOR1>(s);                                        \
      s += dpp_mov<DPP_QUAD_XOR2>(s);                                        \
      s += dpp_mov<DPP_HALF_MIRROR>(s);                                      \
      const float e = __builtin_amdgcn_exp2f(-s); /* sim<=0: no max shift */ \
      if (ix & 1) d1 += e; else d0 += e;                                     \
      if (_own) ev7[ix] = e;                                                 \
      const h16x2 v01 = buf[ix].n[2], v23 = buf[ix].n[3];                    \
      acc.x = fmaf(e, (float)v01.x, acc.x);                                  \
      acc.y = fmaf(e, (float)v01.y, acc.y);                                  \
      acc.z = fmaf(e, (float)v23.x, acc.z);                                  \
      acc.w = fmaf(e, (float)v23.y, acc.w);                                  \
    }                                                                        \
  }

  // Depth-2 pipeline, period-3 rotation, unconditional loads.
  // Rows computed: t=0 -> C0,C1,C2 ; t=3 -> C3,C4,C5 ; epilogue C6.
  // Buffer walk: L0->A L1->B | L2->C C0 L3->A C1 L4->B C2 | L5->C C3
  // L6->A C4 L7c->B C5 | C6(A=row6). Steady state: 14 loads in flight.
  KV A[KW], Bf[KW], Cf[KW];
  LOADROW(A, 0)
  LOADROW(Bf, 1)
#pragma clang loop unroll(disable)
  for (int ty = 0; ty < 6; ty += 3) {  // ty = 0,3 — runtime backedge
    LOADROW(Cf, ty + 2)
    COMPROW(A, ty)
    LOADROW(A, ty + 3)
    COMPROW(Bf, ty + 1)
    LOADROW(Bf, ty + 4)   // ty=3: virtual row 7, clamps to row 6 (redundant)
    COMPROW(Cf, ty + 2)
  }
  COMPROW(A, KW - 1)      // epilogue: row 6 (in A since t=3's L6->A)

  const float inv = 1.0f / (d0 + d1);
  float4 o;
  o.x = acc.x * inv; o.y = acc.y * inv; o.z = acc.z * inv; o.w = acc.w * inv;
  *(float4*)(outp + (size_t)(b * N + n) * C + chn) = o;

  // lane e8 (<7) writes window row e8 of attn, normalized, exactly once.
  // Direct scatter: L3 absorbs it (R3: LDS-coalesced version was slower).
  if (e8 < KW) {
    float* attn_row = attnp + ((size_t)(b * N + n) * NH + g) * KK + e8 * KW;
#pragma unroll
    for (int ix = 0; ix < KW; ++ix) attn_row[ix] = ev7[ix] * inv;
  }
}

extern "C" void kernel_launch(void* const* d_in, const int* in_sizes, int n_in,
                              void* d_out, int out_size, void* d_ws, size_t ws_size,
                              hipStream_t stream) {
  const float* moff = (const float*)d_in[0];  // [B,N,h,2]
  const float* q    = (const float*)d_in[1];  // [B,N,C]
  const float* k    = (const float*)d_in[2];  // [B,N,C]
  const float* v    = (const float*)d_in[3];  // [B,N,C]
  float* out  = (float*)d_out;            // [B,N,C]
  float* attn = out + (size_t)B * N * C;  // [B,N,h,K]
  __half* kv = (__half*)d_ws;             // packed fp16 kv, 8.4 MB

  pack_kv_kernel<<<B * N * NH * 8 / 256, 256, 0, stream>>>(k, v, kv);
  const int grid = B * NH * N / PIX;  // 2048 blocks of 256 threads
  match_attn_kernel<<<grid, 256, 0, stream>>>(moff, q, kv, out, attn);
}

// Round 6
// 110.056 us; speedup vs baseline: 1.0673x; 1.0066x over previous
//
#include <hip/hip_runtime.h>
#include <hip/hip_fp16.h>
#include <math.h>

// MatchAttention fused forward — v7 (v3 structure + head-major kv layout).
// B=2, H=W=64 (N=4096), C=256, h=8 (Ch=32), 7x7=49 window.
//
// Ledger:
// - Load batches survive ONLY across a runtime-loop backedge with no
//   intervening control flow (R8; collapses in R9/R10/R1-v2).
// - TLP null (R0->R2), 2-stream ILP negative (R4), VALU diet ~3us (R2),
//   attn-write coalescing null (R3, L3 absorbs), depth-2 prefetch null
//   (R5: 14 loads verifiably in flight, no gain) -> NOT latency-bound.
// - Model: gather address-processing rate. 49 fully-diverged gather
//   insts/thread x ~64cyc/inst x 32 waves/CU = 100K cyc/CU = 41.8us
//   == measured match time. Total = match + ~68us fixed harness cost
//   (256MiB ws-poison fill ~45us + pack ~3us + launch gaps).
// v7 tests the ONE untested assumption: does TA cost depend on spatial
// locality of lane addresses? Head-major kv [b][g][n][128B] puts a
// wave-inst's 16 lines in a ~4KB neighborhood (vs ~50KB scatter with
// [b][n][g]). Locality-sensitive -> ~25-32us match; line-count-bound ->
// unchanged, declare roofline (100K-cycle gather-pipe ceiling).
constexpr int B = 2, H = 64, W = 64, C = 256, NH = 8, CH = 32;
constexpr int R = 3, KW = 7, KK = 49, N = H * W;
constexpr int PIX = 32;  // pixel-heads per 256-thread block (8 lanes each)
constexpr float LOG2E = 1.4426950408889634f;

typedef _Float16 h16x2 __attribute__((ext_vector_type(2)));

template <int CTRL>
static __device__ __forceinline__ float dpp_mov(float v) {
  union { float f; int i; } u;
  u.f = v;
  u.i = __builtin_amdgcn_update_dpp(u.i, u.i, CTRL, 0xf, 0xf, true);
  return u.f;
}
#define DPP_QUAD_XOR1 0xB1     // quad_perm [1,0,3,2]
#define DPP_QUAD_XOR2 0x4E     // quad_perm [2,3,0,1]
#define DPP_HALF_MIRROR 0x141  // lane i -> 7-i within each 8-lane group

static __device__ __forceinline__ h16x2 h2n(__half2 x) {
  union { __half2 h; h16x2 n; } u;
  u.h = x;
  return u.n;
}

// pack k,v fp32 -> fp16 interleaved, HEAD-MAJOR: [b][g][n][(k0..3 v0..3)x8]
// = 128B per (g,n). k pre-scaled by log2(e): exp2(-log2e*sum|q-k|) ==
// exp(-sum|q-k|). v unscaled.
__global__ void __launch_bounds__(256) pack_kv_kernel(
    const float* __restrict__ kp, const float* __restrict__ vp,
    __half* __restrict__ kv) {
  const int idx = blockIdx.x * 256 + threadIdx.x;  // 0..524287
  const int e8 = idx & 7;
  const int g = (idx >> 3) & 7;
  const int bn = idx >> 6;  // 0..8191 = b*N+n
  const int b = bn >> 12;   // N = 4096
  const int n = bn & (N - 1);
  const float4 kf = *(const float4*)(kp + (size_t)bn * C + g * CH + e8 * 4);
  const float4 vf = *(const float4*)(vp + (size_t)bn * C + g * CH + e8 * 4);
  __half2 o[4];
  o[0] = __floats2half2_rn(kf.x * LOG2E, kf.y * LOG2E);
  o[1] = __floats2half2_rn(kf.z * LOG2E, kf.w * LOG2E);
  o[2] = __floats2half2_rn(vf.x, vf.y);
  o[3] = __floats2half2_rn(vf.z, vf.w);
  *(float4*)(kv + (((size_t)(b * NH + g) * N + n) * 64 + e8 * 8)) = *(float4*)o;
}

union KV { float4 f; __half2 h[4]; h16x2 n[4]; };

__global__ void __launch_bounds__(256, 2) match_attn_kernel(
    const float* __restrict__ moff, const float* __restrict__ qp,
    const __half* __restrict__ kvp, float* __restrict__ outp,
    float* __restrict__ attnp) {
  const int t = threadIdx.x;
  const int e8 = t & 7;  // which 4-channel slice of the head
  const int p = t >> 3;  // pixel within block, 0..31

  // XCD swizzle: blk&7 ~ XCD; XCD x owns (b,g) pairs {2x,2x+1}
  const int xcd = blockIdx.x & 7;
  const int rest = blockIdx.x >> 3;      // 0..255
  const int bg = xcd * 2 + (rest >> 7);  // 0..15
  const int slot = rest & 127;
  const int y = slot >> 1;
  const int x = (slot & 1) * PIX + p;
  const int g = bg & 7;
  const int b = bg >> 3;
  const int n = y * W + x;

  // per-pixel, per-head rounded (dy,dx); rintf == jnp.round (half-to-even)
  const float2 off = *(const float2*)(moff + ((size_t)(b * N + n) * NH + g) * 2);
  const int cy = y + (int)rintf(off.x);
  const int cx = x + (int)rintf(off.y);

  // clamped x offsets in BYTES (head-major: pixel stride 128B)
  int pxo[KW];
#pragma unroll
  for (int i = 0; i < KW; ++i) pxo[i] = min(max(cx + i - R, 0), W - 1) << 7;
  // wave-uniform image base (b,g blockIdx-derived -> SGPR pair);
  // per-lane terms live in the 32-bit voffset -> saddr-form loads.
  const char* __restrict__ kvb =
      (const char*)kvp + (size_t)(b * NH + g) * N * 128;
  const int lane16 = e8 * 16;

  const int chn = g * CH + e8 * 4;
  const float4 q0 = *(const float4*)(qp + (size_t)(b * N + n) * C + chn);
  const __half2 q01 = __floats2half2_rn(q0.x * LOG2E, q0.y * LOG2E);
  const __half2 q23 = __floats2half2_rn(q0.z * LOG2E, q0.w * LOG2E);
  const h16x2 one2 = {(_Float16)1.0f, (_Float16)1.0f};

  float ev7[KW];  // attn weights of the row this lane owns (lane e8 -> row e8)
#pragma unroll
  for (int i = 0; i < KW; ++i) ev7[i] = 0.f;
  float4 acc = {0.f, 0.f, 0.f, 0.f};  // unnormalized e-weighted V sum
  float d0 = 0.f, d1 = 0.f;           // two denom chains

  // row base (bytes, head-major row stride W*128 = 8KB) + lane chunk
#define ROWBASE(iy) ((min(max(cy + (iy)-R, 0), H - 1) << 13) + lane16)
#define LOADROW(buf, iy)                                      \
  {                                                           \
    const int _rb = ROWBASE(iy);                              \
    _Pragma("unroll") for (int ix = 0; ix < KW; ++ix)         \
        buf[ix].f = *(const float4*)(kvb + (_rb + pxo[ix]));  \
  }
#define COMPROW(buf, iy)                                                     \
  {                                                                          \
    const bool _own = ((iy) == e8);                                          \
    _Pragma("unroll") for (int ix = 0; ix < KW; ++ix) {                      \
      const h16x2 d01 = h2n(__habs2(__hsub2(q01, buf[ix].h[0])));            \
      const h16x2 d23 = h2n(__habs2(__hsub2(q23, buf[ix].h[1])));            \
      float s = __builtin_amdgcn_fdot2(                                      \
          d01, one2, __builtin_amdgcn_fdot2(d23, one2, 0.0f, false), false); \
      s += dpp_mov<DPP_QUAD_XOR1>(s);                                        \
      s += dpp_mov<DPP_QUAD_XOR2>(s);                                        \
      s += dpp_mov<DPP_HALF_MIRROR>(s);                                      \
      const float e = __builtin_amdgcn_exp2f(-s); /* sim<=0: no max shift */ \
      if (ix & 1) d1 += e; else d0 += e;                                     \
      if (_own) ev7[ix] = e;                                                 \
      const h16x2 v01 = buf[ix].n[2], v23 = buf[ix].n[3];                    \
      acc.x = fmaf(e, (float)v01.x, acc.x);                                  \
      acc.y = fmaf(e, (float)v01.y, acc.y);                                  \
      acc.z = fmaf(e, (float)v23.x, acc.z);                                  \
      acc.w = fmaf(e, (float)v23.y, acc.w);                                  \
    }                                                                        \
  }

  KV A[KW], Bf[KW];
  LOADROW(A, 0)  // prologue: row 0 in flight
#pragma clang loop unroll(disable)
  for (int ty = 0; ty < KW - 1; ty += 2) {  // ty = 0,2,4 — runtime backedge
    LOADROW(Bf, ty + 1)   // issue row ty+1 while row ty computes
    COMPROW(A, ty)
    LOADROW(A, ty + 2)    // issue row ty+2; crosses the backedge -> cannot
    COMPROW(Bf, ty + 1)   //   be sunk by the scheduler (R8 evidence)
  }
  COMPROW(A, KW - 1)      // epilogue: row 6

  const float inv = 1.0f / (d0 + d1);
  float4 o;
  o.x = acc.x * inv; o.y = acc.y * inv; o.z = acc.z * inv; o.w = acc.w * inv;
  *(float4*)(outp + (size_t)(b * N + n) * C + chn) = o;

  // lane e8 (<7) writes window row e8 of attn, normalized, exactly once.
  // Direct scatter: L3 absorbs it (R3: LDS-coalesced version was slower).
  if (e8 < KW) {
    float* attn_row = attnp + ((size_t)(b * N + n) * NH + g) * KK + e8 * KW;
#pragma unroll
    for (int ix = 0; ix < KW; ++ix) attn_row[ix] = ev7[ix] * inv;
  }
}

extern "C" void kernel_launch(void* const* d_in, const int* in_sizes, int n_in,
                              void* d_out, int out_size, void* d_ws, size_t ws_size,
                              hipStream_t stream) {
  const float* moff = (const float*)d_in[0];  // [B,N,h,2]
  const float* q    = (const float*)d_in[1];  // [B,N,C]
  const float* k    = (const float*)d_in[2];  // [B,N,C]
  const float* v    = (const float*)d_in[3];  // [B,N,C]
  float* out  = (float*)d_out;            // [B,N,C]
  float* attn = out + (size_t)B * N * C;  // [B,N,h,K]
  __half* kv = (__half*)d_ws;             // packed fp16 kv, 8.4 MB

  pack_kv_kernel<<<B * N * NH * 8 / 256, 256, 0, stream>>>(k, v, kv);
  const int grid = B * NH * N / PIX;  // 2048 blocks of 256 threads
  match_attn_kernel<<<grid, 256, 0, stream>>>(moff, q, kv, out, attn);
}